// Round 8
// baseline (221.741 us; speedup 1.0000x reference)
//
#include <hip/hip_runtime.h>

#define D_DIM 640
#define M_DIM 1024
#define B_DIM 32
#define BK 32
#define OUT_ROW 205120  // 640*641/2
#define NBLK 480        // gemm grid; co-residency guaranteed (>=2 blocks/CU capacity)

typedef __bf16 bf16x8 __attribute__((ext_vector_type(8)));
typedef float f32x4 __attribute__((ext_vector_type(4)));

__device__ __forceinline__ unsigned short f2bf(float f) {
    union { float f; unsigned int u; } c; c.f = f;
    unsigned int u = c.u;
    unsigned int r = (u + 0x7fffu + ((u >> 16) & 1u)) >> 16;
    return (unsigned short)r;
}

__device__ __forceinline__ void gload_lds16(const unsigned short* g, unsigned short* l) {
    __builtin_amdgcn_global_load_lds(
        (const __attribute__((address_space(1))) unsigned int*)g,
        (__attribute__((address_space(3))) unsigned int*)l,
        16, 0, 0);
}

__device__ __forceinline__ float block_reduce_256(float s) {
    #pragma unroll
    for (int off = 32; off > 0; off >>= 1) s += __shfl_down(s, off, 64);
    __shared__ float red[4];
    if ((threadIdx.x & 63) == 0) red[threadIdx.x >> 6] = s;
    __syncthreads();
    return red[0] + red[1] + red[2] + red[3];
}

__device__ __forceinline__ float aload(const float* p) {
    return __hip_atomic_load(p, __ATOMIC_RELAXED, __HIP_MEMORY_SCOPE_AGENT);
}

// Kernel 1: fp32 -> bf16 cast + per-row sum of squares; zeroes accumulators
// and the grid-barrier counter consumed by the gemm kernel.
__global__ void cast_diag_kernel(const float* __restrict__ x,
                                 unsigned short* __restrict__ xb,
                                 float* __restrict__ diag,
                                 float* __restrict__ rowsum,
                                 float* __restrict__ tot,
                                 unsigned int* __restrict__ ctr) {
    const size_t row = blockIdx.x;
    const int t = threadIdx.x;
    const float4 v = ((const float4*)(x + row * M_DIM))[t];
    float s = v.x * v.x + v.y * v.y + v.z * v.z + v.w * v.w;
    ushort4 o;
    o.x = f2bf(v.x); o.y = f2bf(v.y); o.z = f2bf(v.z); o.w = f2bf(v.w);
    ((ushort4*)(xb + row * M_DIM))[t] = o;
    float ssum = block_reduce_256(s);
    if (t == 0) { diag[row] = ssum; rowsum[row] = 0.f; }
    if (t == 1 && row < B_DIM) tot[row] = 0.f;
    if (t == 2 && row == 0)
        __hip_atomic_store(ctr, 0u, __ATOMIC_RELAXED, __HIP_MEMORY_SCOPE_AGENT);
}

// Kernel 2: symmetric batched G = X X^T (upper-tri 128-tiles, R4/R7 K-loop:
// 3 LDS phases / 48 KB, fenced vmcnt(8) pipeline), then dcov + rowsum/tot
// atomics, then a DEVICE SPIN-BARRIER (all 480 blocks co-resident: LDS caps
// at 3 blocks/CU -> capacity >= 768), then centering + triu output written
// straight from registers. dcov is never materialized; no third kernel.
__global__ __launch_bounds__(256, 2)
void gemm_out_kernel(const unsigned short* __restrict__ xb,
                     const float* __restrict__ diag,
                     float* __restrict__ rowsum,
                     float* __restrict__ tot,
                     unsigned int* __restrict__ ctr,
                     float* __restrict__ out) {
    // 3 phases x (A 4096 + B 4096 shorts) = 24576 shorts = 48 KB
    __shared__ __align__(16) unsigned short smem[24576];

    const int id = blockIdx.x;
    const int bt = (id & 7) * 4 + ((id >> 3) & 3);  // tiles of a batch share an XCD
    int p = id >> 5;                                 // 0..14 tile-pair index
    int it = 0, off = p;
    while (off >= 5 - it) { off -= 5 - it; ++it; }
    const int jt = it + off;
    const bool diagTile = (it == jt);

    const int tid = threadIdx.x;
    const int w = tid >> 6, l = tid & 63;
    const int wy = w >> 1, wx = w & 1;
    const int lm = l & 15, quad = l >> 4;

    const unsigned short* gA = xb + ((size_t)bt * D_DIM + it * 128) * M_DIM;
    const unsigned short* gB = xb + ((size_t)bt * D_DIM + jt * 128) * M_DIM;

    const int r0 = tid >> 2;
    const int cl = (((tid & 3) ^ ((tid >> 3) & 3)) << 3);  // XOR chunk swizzle
    const size_t aoff1 = (size_t)r0 * M_DIM + cl;
    const size_t aoff2 = aoff1 + (size_t)64 * M_DIM;
    const int ldst = tid * 8;

    auto issue = [&](int k, int ph) {
        unsigned short* sA = smem + ph * 8192;
        unsigned short* sB = sA + 4096;
        const int koff = k * BK;
        gload_lds16(gA + aoff1 + koff, sA + ldst);
        gload_lds16(gA + aoff2 + koff, sA + ldst + 2048);
        gload_lds16(gB + aoff1 + koff, sB + ldst);
        gload_lds16(gB + aoff2 + koff, sB + ldst + 2048);
    };

    f32x4 acc[4][4];
    const f32x4 zero = {0.f, 0.f, 0.f, 0.f};
    #pragma unroll
    for (int i = 0; i < 4; i++)
        #pragma unroll
        for (int j = 0; j < 4; j++) acc[i][j] = zero;

    const int sw = ((quad ^ ((lm >> 1) & 3)) << 3);

    issue(0, 0); issue(1, 1); issue(2, 2);

    int ph = 0;
    for (int k = 0; k < 32; ++k) {
        if (k < 30)       asm volatile("s_waitcnt vmcnt(8)" ::: "memory");
        else if (k == 30) asm volatile("s_waitcnt vmcnt(4)" ::: "memory");
        else              asm volatile("s_waitcnt vmcnt(0)" ::: "memory");
        asm volatile("s_barrier" ::: "memory");

        const unsigned short* sA = smem + ph * 8192;
        const unsigned short* sB = sA + 4096;
        bf16x8 af[4], bfr[4];
        #pragma unroll
        for (int mi = 0; mi < 4; mi++)
            af[mi] = *(const bf16x8*)&sA[(wy * 64 + mi * 16 + lm) * BK + sw];
        #pragma unroll
        for (int ni = 0; ni < 4; ni++)
            bfr[ni] = *(const bf16x8*)&sB[(wx * 64 + ni * 16 + lm) * BK + sw];

        #pragma unroll
        for (int mi = 0; mi < 4; mi++)
            #pragma unroll
            for (int ni = 0; ni < 4; ni++)
                acc[mi][ni] = __builtin_amdgcn_mfma_f32_16x16x32_bf16(
                    af[mi], bfr[ni], acc[mi][ni], 0, 0, 0);

        asm volatile("s_barrier" ::: "memory");
        if (k + 3 < 32) issue(k + 3, ph);
        ph = (ph == 2) ? 0 : ph + 1;
    }

    // stage diag slices in LDS (reuse smem; safe after final barrier)
    float* sd = (float*)smem;
    if (tid < 128) sd[tid] = diag[(size_t)bt * D_DIM + it * 128 + tid];
    else           sd[tid] = diag[(size_t)bt * D_DIM + jt * 128 + (tid - 128)];
    __syncthreads();

    const float temp = 7.62939453125e-07f;  // 1/(2*640*1024)
    float* rs = rowsum + (size_t)bt * D_DIM;
    float ts = 0.f;
    float cp[4] = {0.f, 0.f, 0.f, 0.f};

    // Pass 1: rowsum/tot accumulation (dcov values stay in acc registers).
    #pragma unroll
    for (int mi = 0; mi < 4; mi++) {
        #pragma unroll
        for (int r = 0; r < 4; r++) {
            const int lrow = wy * 64 + mi * 16 + quad * 4 + r;
            const int grow = it * 128 + lrow;
            const float di = sd[lrow];
            float rp = 0.f;
            #pragma unroll
            for (int ni = 0; ni < 4; ni++) {
                const int lcol = wx * 64 + ni * 16 + lm;
                const float dj = sd[128 + lcol];
                const float g = acc[mi][ni][r];
                const float v = sqrtf(fmaf(temp, fmaxf(di + dj - 2.f * g, 0.f), 1e-5f));
                rp += v;
                cp[ni] += v;
            }
            ts += rp;
            rp += __shfl_down(rp, 8, 16);
            rp += __shfl_down(rp, 4, 16);
            rp += __shfl_down(rp, 2, 16);
            rp += __shfl_down(rp, 1, 16);
            if (lm == 0) atomicAdd(&rs[grow], rp);
        }
    }
    if (!diagTile) {
        #pragma unroll
        for (int ni = 0; ni < 4; ni++) {
            float c = cp[ni];
            c += __shfl_down(c, 32);
            c += __shfl_down(c, 16);
            if (l < 16) atomicAdd(&rs[jt * 128 + wx * 64 + ni * 16 + lm], c);
        }
    }
    float bs = block_reduce_256(ts);
    if (tid == 0) atomicAdd(&tot[bt], diagTile ? bs : 2.f * bs);

    // ---- device-wide spin barrier (all NBLK blocks are co-resident) ----
    __threadfence();        // each wave drains its atomics to coherent point
    __syncthreads();        // all 4 waves of this block done
    if (tid == 0) {
        atomicAdd(ctr, 1u);
        while (__hip_atomic_load(ctr, __ATOMIC_ACQUIRE, __HIP_MEMORY_SCOPE_AGENT) < NBLK)
            __builtin_amdgcn_s_sleep(2);
    }
    __syncthreads();

    // ---- centering + triu output straight from registers ----
    const float inv_d = 1.f / (float)D_DIM;
    const float tm = aload(&tot[bt]) * (inv_d * inv_d);
    float cmj[4];
    #pragma unroll
    for (int ni = 0; ni < 4; ni++)
        cmj[ni] = aload(&rs[jt * 128 + wx * 64 + ni * 16 + lm]) * inv_d;

    float* obase = out + (size_t)bt * OUT_ROW;
    #pragma unroll
    for (int mi = 0; mi < 4; mi++) {
        #pragma unroll
        for (int r = 0; r < 4; r++) {
            const int lrow = wy * 64 + mi * 16 + quad * 4 + r;
            const int grow = it * 128 + lrow;
            const float di = sd[lrow];
            const float rmi = aload(&rs[grow]) * inv_d;
            float* orow = obase + (size_t)grow * D_DIM - (size_t)grow * (grow - 1) / 2 - grow;
            #pragma unroll
            for (int ni = 0; ni < 4; ni++) {
                const int gcol = jt * 128 + wx * 64 + ni * 16 + lm;
                const float dj = sd[128 + (wx * 64 + ni * 16 + lm)];
                const float g = acc[mi][ni][r];
                const float v = sqrtf(fmaf(temp, fmaxf(di + dj - 2.f * g, 0.f), 1e-5f));
                if (!diagTile || gcol >= grow)
                    orow[gcol] = v - rmi - cmj[ni] + tm;
            }
        }
    }
}

extern "C" void kernel_launch(void* const* d_in, const int* in_sizes, int n_in,
                              void* d_out, int out_size, void* d_ws, size_t ws_size,
                              hipStream_t stream) {
    const float* x = (const float*)d_in[0];
    float* out = (float*)d_out;

    char* ws = (char*)d_ws;
    unsigned short* xb = (unsigned short*)ws;        // 41,943,040 B
    size_t off = 41943040;
    float* diag = (float*)(ws + off);     off += 81920;
    float* rowsum = (float*)(ws + off);   off += 81920;
    float* tot = (float*)(ws + off);      off += 256;
    unsigned int* ctr = (unsigned int*)(ws + off); off += 256;

    cast_diag_kernel<<<dim3(B_DIM * D_DIM), 256, 0, stream>>>(x, xb, diag, rowsum, tot, ctr);
    gemm_out_kernel<<<dim3(NBLK), 256, 0, stream>>>(xb, diag, rowsum, tot, ctr, out);
}